// Round 5
// baseline (400.306 us; speedup 1.0000x reference)
//
#include <hip/hip_runtime.h>

// DYDConv2d: dynamic per-pixel depthwise 3x3 conv, stride 1, pad 1.
// input  [8,64,128,128] fp32; weight [8,64,3,3,128,128] fp32 (302 MB, single-use);
// output [8,64,128,128] fp32.
//
// Memory-bound: min traffic ~369 MB -> ~56 us at 6.6 TB/s achieved (fill BW).
// Wall dur includes ~290 us fixed harness resets (1.2 GB ws fill @183 us etc);
// conv kernel bracketed at 60-110 us. R4 round: 2 rows x 4 cols per thread —
// calibration: positive iff issue/latency-bound, neutral iff already BW-bound.

typedef float vfloat4 __attribute__((ext_vector_type(4)));

namespace {
constexpr int kH = 128;
constexpr int kW = 128;
constexpr int kPlane = kH * kW;                               // 16384
constexpr int kThreadsTotal = 8 * 64 * (kH / 2) * (kW / 4);   // 1,048,576
}

__global__ __launch_bounds__(256) void dyd_conv_kernel(
    const float* __restrict__ in,
    const float* __restrict__ wgt,
    float* __restrict__ out) {
    int idx = blockIdx.x * blockDim.x + threadIdx.x;
    int lane = threadIdx.x & 63;
    // 32 threads per output row (4 cols each); each thread does 2 rows.
    int ow0 = (idx & 31) << 2;          // 0,4,...,124 (16B-aligned)
    int oh0 = ((idx >> 5) & 63) << 1;   // 0,2,...,126
    int bc  = idx >> 11;                // b*C + c

    const float* inp = in + (size_t)bc * kPlane;
    const float* wp  = wgt + (size_t)bc * (9 * kPlane) + oh0 * kW + ow0;

    // Input rows oh0-1 .. oh0+2 (4 rows cover both output rows' 3-taps).
    vfloat4 m[4];
#pragma unroll
    for (int r = 0; r < 4; ++r) {
        int ih = oh0 + r - 1;
        vfloat4 v = {0.f, 0.f, 0.f, 0.f};
        if (ih >= 0 && ih < kH)
            v = *(const vfloat4*)(inp + ih * kW + ow0);
        m[r] = v;
    }

    // Halo cols from neighbor lanes; pad lanes are exactly the masked ones.
    float lft[4], rgt[4];
#pragma unroll
    for (int r = 0; r < 4; ++r) {
        lft[r] = __shfl(m[r].w, lane - 1);   // col ow0-1
        rgt[r] = __shfl(m[r].x, lane + 1);   // col ow0+4
    }
    if (ow0 == 0)      { lft[0] = lft[1] = lft[2] = lft[3] = 0.f; }
    if (ow0 + 4 >= kW) { rgt[0] = rgt[1] = rgt[2] = rgt[3] = 0.f; }

    // 18 independent nontemporal weight loads (single-use -> keep L2 for input).
    vfloat4 w[3][3][2];
#pragma unroll
    for (int i = 0; i < 3; ++i)
#pragma unroll
        for (int j = 0; j < 3; ++j)
#pragma unroll
            for (int r = 0; r < 2; ++r)
                w[i][j][r] = __builtin_nontemporal_load(
                    (const vfloat4*)(wp + (i * 3 + j) * kPlane + r * kW));

    float acc[2][4] = {};
#pragma unroll
    for (int r = 0; r < 2; ++r)
#pragma unroll
        for (int i = 0; i < 3; ++i) {
            vfloat4 mm = m[i + r];
            float l = lft[i + r], rr = rgt[i + r];
            vfloat4 w0 = w[i][0][r], w1 = w[i][1][r], w2 = w[i][2][r];
            acc[r][0] += w0.x * l    + w1.x * mm.x + w2.x * mm.y;
            acc[r][1] += w0.y * mm.x + w1.y * mm.y + w2.y * mm.z;
            acc[r][2] += w0.z * mm.y + w1.z * mm.z + w2.z * mm.w;
            acc[r][3] += w0.w * mm.z + w1.w * mm.w + w2.w * rr;
        }

#pragma unroll
    for (int r = 0; r < 2; ++r) {
        vfloat4 o = {acc[r][0], acc[r][1], acc[r][2], acc[r][3]};
        __builtin_nontemporal_store(
            o, (vfloat4*)(out + (size_t)bc * kPlane + (oh0 + r) * kW + ow0));
    }
}

extern "C" void kernel_launch(void* const* d_in, const int* in_sizes, int n_in,
                              void* d_out, int out_size, void* d_ws, size_t ws_size,
                              hipStream_t stream) {
    const float* in  = (const float*)d_in[0];
    const float* wgt = (const float*)d_in[1];
    float* out = (float*)d_out;
    constexpr int kBlock = 256;
    constexpr int kGrid = kThreadsTotal / kBlock;   // 4096
    dyd_conv_kernel<<<kGrid, kBlock, 0, stream>>>(in, wgt, out);
}